// Round 1
// baseline (1126.509 us; speedup 1.0000x reference)
//
#include <hip/hip_runtime.h>
#include <hip/hip_bf16.h>
#include <stdint.h>

#define SEQ   2048
#define HID   3072
#define NHEADS 24
#define HDIM  128
#define MLPD  12288
#define NCOL1 21504   // 3*HID + MLPD
#define NCOL2 15360   // HID + MLPD
#define MOD3  9216    // 3*HID

typedef __attribute__((ext_vector_type(4))) float f32x4;
typedef __attribute__((ext_vector_type(8))) short bf16x8;
typedef __attribute__((ext_vector_type(4))) unsigned short u16x4;
typedef __attribute__((ext_vector_type(2))) unsigned short u16x2;

__device__ __forceinline__ unsigned short f2bf(float f){
  unsigned u = __float_as_uint(f);
  u = (u + 0x7fffu + ((u >> 16) & 1u)) >> 16;   // RTNE
  return (unsigned short)u;
}

__device__ __forceinline__ void gload_lds16(const void* g, void* l){
  __builtin_amdgcn_global_load_lds(
      (const __attribute__((address_space(1))) unsigned int*)g,
      (__attribute__((address_space(3))) unsigned int*)l, 16, 0, 0);
}

// ---------------------------------------------------------------- small ops
__global__ void silu_kernel(const float* __restrict__ vec, float* __restrict__ sv){
  int i = blockIdx.x * 256 + threadIdx.x;
  if (i < HID){ float v = vec[i]; sv[i] = v / (1.f + __expf(-v)); }
}

// mod = silu(vec) @ mod_w + mod_b   (3072 x 9216), split-K for CU coverage
__global__ void mod_gemv(const float* __restrict__ sv, const float* __restrict__ W,
                         const float* __restrict__ b, float* __restrict__ mod){
  int n  = blockIdx.x * 32 + (threadIdx.x & 31);
  int ks = threadIdx.x >> 5;               // 0..7, each 384 k
  float acc = 0.f;
  int k0 = ks * 384;
  #pragma unroll 4
  for (int k = k0; k < k0 + 384; ++k)
    acc += sv[k] * W[(size_t)k * MOD3 + n];
  __shared__ float red[8][32];
  red[ks][threadIdx.x & 31] = acc;
  __syncthreads();
  if (ks == 0){
    float a = 0.f;
    #pragma unroll
    for (int i = 0; i < 8; ++i) a += red[i][threadIdx.x & 31];
    mod[n] = a + b[n];
  }
}

// per-row LayerNorm + (1+scale)*xn + shift, emit bf16
__global__ __launch_bounds__(256)
void ln_mod_kernel(const float* __restrict__ x, const float* __restrict__ mod,
                   unsigned short* __restrict__ xmod){
  int l = blockIdx.x, t = threadIdx.x;
  const float* row = x + (size_t)l * HID;
  f32x4 v[3];
  float s = 0.f, s2 = 0.f;
  #pragma unroll
  for (int i = 0; i < 3; ++i){
    v[i] = *(const f32x4*)(row + (t + i * 256) * 4);
    #pragma unroll
    for (int j = 0; j < 4; ++j){ s += v[i][j]; s2 += v[i][j] * v[i][j]; }
  }
  #pragma unroll
  for (int m = 1; m < 64; m <<= 1){ s += __shfl_xor(s, m, 64); s2 += __shfl_xor(s2, m, 64); }
  __shared__ float red[8];
  int wv = t >> 6, ln = t & 63;
  if (ln == 0){ red[wv] = s; red[4 + wv] = s2; }
  __syncthreads();
  s  = red[0] + red[1] + red[2] + red[3];
  s2 = red[4] + red[5] + red[6] + red[7];
  float mu  = s * (1.f / HID);
  float var = s2 * (1.f / HID) - mu * mu;
  float rs  = rsqrtf(var + 1e-6f);
  #pragma unroll
  for (int i = 0; i < 3; ++i){
    int c = (t + i * 256) * 4;
    f32x4 sh = *(const f32x4*)(mod + c);
    f32x4 sc = *(const f32x4*)(mod + HID + c);
    u16x4 o;
    #pragma unroll
    for (int j = 0; j < 4; ++j){
      float xn = (v[i][j] - mu) * rs;
      o[j] = f2bf((1.f + sc[j]) * xn + sh[j]);
    }
    *(u16x4*)(xmod + (size_t)l * HID + c) = o;
  }
}

// fp32 (R x C) -> bf16 (C x R)
__global__ __launch_bounds__(256)
void transpose_f2b(const float* __restrict__ in, unsigned short* __restrict__ out,
                   int R, int C){
  __shared__ float tile[64][65];
  int rt = blockIdx.y * 64, ct = blockIdx.x * 64;
  int t = threadIdx.x;
  int r0 = t >> 4, c0 = (t & 15) * 4;
  #pragma unroll
  for (int ph = 0; ph < 4; ++ph){
    int r = r0 + ph * 16;
    f32x4 v = *(const f32x4*)(in + (size_t)(rt + r) * C + ct + c0);
    tile[r][c0 + 0] = v[0]; tile[r][c0 + 1] = v[1];
    tile[r][c0 + 2] = v[2]; tile[r][c0 + 3] = v[3];
  }
  __syncthreads();
  #pragma unroll
  for (int ph = 0; ph < 4; ++ph){
    int r = r0 + ph * 16;
    u16x4 o;
    #pragma unroll
    for (int i = 0; i < 4; ++i) o[i] = f2bf(tile[c0 + i][r]);
    *(u16x4*)(out + (size_t)(ct + r) * R + rt + c0) = o;
  }
}

// per-head bf16 (R x C) -> bf16 (C x R)   (V -> V^T)
__global__ __launch_bounds__(256)
void transpose_b2b_head(const unsigned short* __restrict__ in,
                        unsigned short* __restrict__ out, int R, int C){
  __shared__ unsigned short tile[64][68];
  int h = blockIdx.z;
  const unsigned short* inh = in + (size_t)h * R * C;
  unsigned short* outh = out + (size_t)h * R * C;
  int rt = blockIdx.y * 64, ct = blockIdx.x * 64;
  int t = threadIdx.x;
  int r0 = t >> 4, c0 = (t & 15) * 4;
  #pragma unroll
  for (int ph = 0; ph < 4; ++ph){
    int r = r0 + ph * 16;
    u16x4 v = *(const u16x4*)(inh + (size_t)(rt + r) * C + ct + c0);
    tile[r][c0 + 0] = v[0]; tile[r][c0 + 1] = v[1];
    tile[r][c0 + 2] = v[2]; tile[r][c0 + 3] = v[3];
  }
  __syncthreads();
  #pragma unroll
  for (int ph = 0; ph < 4; ++ph){
    int r = r0 + ph * 16;
    u16x4 o;
    #pragma unroll
    for (int i = 0; i < 4; ++i) o[i] = tile[c0 + i][r];
    *(u16x4*)(outh + (size_t)(ct + r) * R + rt + c0) = o;
  }
}

// RMS-norm + RoPE for q,k; passthrough v. One wave per (l, head).
__global__ void qkv_prep(const float* __restrict__ hbuf, const float* __restrict__ pe,
                         const float* __restrict__ qscale, const float* __restrict__ kscale,
                         unsigned short* __restrict__ qb, unsigned short* __restrict__ kb,
                         unsigned short* __restrict__ vb){
  int l = blockIdx.x, hh = blockIdx.y, lane = threadIdx.x;  // 64 threads
  const float* row = hbuf + (size_t)l * NCOL1;
  int d = lane * 2;
  float2 q = *(const float2*)(row + hh * HDIM + d);
  float2 k = *(const float2*)(row + HID + hh * HDIM + d);
  float2 v = *(const float2*)(row + 2 * HID + hh * HDIM + d);
  float sq = q.x * q.x + q.y * q.y;
  float sk = k.x * k.x + k.y * k.y;
  #pragma unroll
  for (int m = 1; m < 64; m <<= 1){ sq += __shfl_xor(sq, m, 64); sk += __shfl_xor(sk, m, 64); }
  float rq = rsqrtf(sq * (1.f / HDIM) + 1e-6f);
  float rk = rsqrtf(sk * (1.f / HDIM) + 1e-6f);
  float2 qs2 = *(const float2*)(qscale + d);
  float2 ks2 = *(const float2*)(kscale + d);
  float q0 = q.x * rq * qs2.x, q1 = q.y * rq * qs2.y;
  float k0 = k.x * rk * ks2.x, k1 = k.y * rk * ks2.y;
  f32x4 p4 = *(const f32x4*)(pe + (size_t)l * 256 + lane * 4);  // [p][a][b]
  const float sscl = 0.08838834764831845f;  // 1/sqrt(128), folded into q
  float qo0 = (p4[0] * q0 + p4[1] * q1) * sscl;
  float qo1 = (p4[2] * q0 + p4[3] * q1) * sscl;
  float ko0 =  p4[0] * k0 + p4[1] * k1;
  float ko1 =  p4[2] * k0 + p4[3] * k1;
  size_t base = ((size_t)hh * SEQ + l) * HDIM + d;
  u16x2 o;
  o[0] = f2bf(qo0); o[1] = f2bf(qo1); *(u16x2*)(qb + base) = o;
  o[0] = f2bf(ko0); o[1] = f2bf(ko1); *(u16x2*)(kb + base) = o;
  o[0] = f2bf(v.x); o[1] = f2bf(v.y); *(u16x2*)(vb + base) = o;
}

__device__ __forceinline__ float gelu_tanh(float x){
  float u = 0.7978845608028654f * (x + 0.044715f * x * x * x);
  float t = 1.f - 2.f / (__expf(2.f * u) + 1.f);   // tanh(u)
  return 0.5f * x * (1.f + t);
}

__global__ void gelu_kernel(const float* __restrict__ hbuf, unsigned short* __restrict__ a2){
  int l = blockIdx.y;
  int xi = blockIdx.x * 256 + threadIdx.x;          // 0..3071 (float4 groups)
  f32x4 v = *(const f32x4*)(hbuf + (size_t)l * NCOL1 + 3 * HID + xi * 4);
  u16x4 o;
  #pragma unroll
  for (int j = 0; j < 4; ++j) o[j] = f2bf(gelu_tanh(v[j]));
  *(u16x4*)(a2 + (size_t)l * NCOL2 + HID + xi * 4) = o;
}

// ------------------------------------------------------------- bt-GEMM m97
// C[M,N] = A[M,K](bf16,rm) @ BT[N,K]^T (bf16,rm) + bias;  EPI1: out = x + gate*(.)
template<int EPI>
__global__ __launch_bounds__(256)
void gemm_bt(const unsigned short* __restrict__ A, const unsigned short* __restrict__ BT,
             const float* __restrict__ bias, float* __restrict__ Cout,
             const float* __restrict__ xres, const float* __restrict__ gate,
             int M, int N, int K){
  __shared__ unsigned short Asm[2][128 * 32];
  __shared__ unsigned short Bsm[2][128 * 32];
  int bn = blockIdx.x, bm = blockIdx.y;
  int tid = threadIdx.x;
  int wave = tid >> 6, lane = tid & 63, lg = lane >> 4, lr = lane & 15;
  int wr = wave >> 1, wc = wave & 1;
  const unsigned short* At = A  + (size_t)bm * 128 * K;
  const unsigned short* Bt = BT + (size_t)bn * 128 * K;

  const f32x4 fzero = 0.0f;
  f32x4 acc[4][4];
  #pragma unroll
  for (int i = 0; i < 4; ++i)
    #pragma unroll
    for (int j = 0; j < 4; ++j) acc[i][j] = fzero;

  auto stage = [&](int buf, int kt){
    const unsigned short* Ak = At + kt * 32;
    const unsigned short* Bk = Bt + kt * 32;
    #pragma unroll
    for (int j = 0; j < 2; ++j){
      int G = j * 256 + tid;          // 16B granule id, 512 per 8KB tile
      int row = G >> 2, cg = G & 3;
      gload_lds16(Ak + (size_t)row * K + cg * 8, (void*)&Asm[buf][(j * 256 + wave * 64) * 8]);
      gload_lds16(Bk + (size_t)row * K + cg * 8, (void*)&Bsm[buf][(j * 256 + wave * 64) * 8]);
    }
  };

  int nk = K / 32;
  stage(0, 0);
  for (int kt = 0; kt < nk; ++kt){
    __syncthreads();
    if (kt + 1 < nk) stage((kt + 1) & 1, kt + 1);
    int buf = kt & 1;
    bf16x8 af[4], bfr[4];
    #pragma unroll
    for (int m = 0; m < 4; ++m)
      af[m] = *(const bf16x8*)&Asm[buf][(wr * 64 + m * 16 + lr) * 32 + lg * 8];
    #pragma unroll
    for (int n = 0; n < 4; ++n)
      bfr[n] = *(const bf16x8*)&Bsm[buf][(wc * 64 + n * 16 + lr) * 32 + lg * 8];
    #pragma unroll
    for (int m = 0; m < 4; ++m)
      #pragma unroll
      for (int n = 0; n < 4; ++n)
        acc[m][n] = __builtin_amdgcn_mfma_f32_16x16x32_bf16(af[m], bfr[n], acc[m][n], 0, 0, 0);
  }
  #pragma unroll
  for (int m = 0; m < 4; ++m)
    #pragma unroll
    for (int n = 0; n < 4; ++n){
      int col = bn * 128 + wc * 64 + n * 16 + lr;
      float bv = bias[col];
      #pragma unroll
      for (int jj = 0; jj < 4; ++jj){
        int row = bm * 128 + wr * 64 + m * 16 + lg * 4 + jj;
        float r = acc[m][n][jj] + bv;
        if constexpr (EPI == 0) Cout[(size_t)row * N + col] = r;
        else Cout[(size_t)row * N + col] = xres[(size_t)row * N + col] + gate[col] * r;
      }
    }
}

// -------------------------------------------------------- flash attention
// grid (SEQ/64, NHEADS); 4 waves x 16 q-rows; KV tiles of 64.
__global__ __launch_bounds__(256)
void attn_kernel(const unsigned short* __restrict__ qb, const unsigned short* __restrict__ kb,
                 const unsigned short* __restrict__ vt, unsigned short* __restrict__ a2){
  __shared__ unsigned short Ksm[64 * 128];   // [kv][d], XOR-swizzled
  __shared__ unsigned short Vsm[128 * 64];   // [d][kv], XOR-swizzled
  __shared__ unsigned short Psm[4][16 * 64]; // per-wave [q][kv], XOR-swizzled
  int qt = blockIdx.x, hh = blockIdx.y;
  int tid = threadIdx.x, wave = tid >> 6, lane = tid & 63, lg = lane >> 4, lr = lane & 15;
  const unsigned short* Kh = kb + (size_t)hh * SEQ * HDIM;
  const unsigned short* Vh = vt + (size_t)hh * HDIM * SEQ;
  const unsigned short* Qh = qb + (size_t)hh * SEQ * HDIM;
  int q0 = qt * 64 + wave * 16;

  bf16x8 aq[4];
  #pragma unroll
  for (int kk = 0; kk < 4; ++kk)
    aq[kk] = *(const bf16x8*)(Qh + (size_t)(q0 + lr) * HDIM + kk * 32 + lg * 8);

  const f32x4 fzero = 0.0f;
  f32x4 acc_o[8];
  #pragma unroll
  for (int n = 0; n < 8; ++n) acc_o[n] = fzero;
  float mrun[4] = {-1e30f, -1e30f, -1e30f, -1e30f};
  float lrun[4] = {0.f, 0.f, 0.f, 0.f};

  for (int t = 0; t < SEQ / 64; ++t){
    __syncthreads();                       // everyone done reading prev K/V
    const unsigned short* Kt = Kh + (size_t)t * 64 * HDIM;
    const unsigned short* Vt = Vh + t * 64;
    #pragma unroll
    for (int r = 0; r < 4; ++r){
      int G  = r * 256 + tid;
      int Gs = G ^ ((G >> 4) & 7);        // K: 256B rows, swizzle source
      gload_lds16(Kt + Gs * 8, (void*)&Ksm[(r * 256 + wave * 64) * 8]);
      int Gv = G ^ ((G >> 3) & 7);        // V^T: 128B rows
      gload_lds16(Vt + (size_t)(Gv >> 3) * SEQ + (Gv & 7) * 8,
                  (void*)&Vsm[(r * 256 + wave * 64) * 8]);
    }
    __syncthreads();                       // staged (barrier drains vmcnt)

    f32x4 sacc[4];
    #pragma unroll
    for (int j = 0; j < 4; ++j) sacc[j] = fzero;
    #pragma unroll
    for (int j = 0; j < 4; ++j){
      int kv = j * 16 + lr;
      #pragma unroll
      for (int kk = 0; kk < 4; ++kk){
        int bo = kv * 256 + (kk * 32 + lg * 8) * 2;
        bo ^= (kv & 7) << 4;
        bf16x8 bk = *(const bf16x8*)((const char*)Ksm + bo);
        sacc[j] = __builtin_amdgcn_mfma_f32_16x16x32_bf16(aq[kk], bk, sacc[j], 0, 0, 0);
      }
    }
    // online softmax (rows lg*4+jj, 16-lane group reduce)
    float scl[4], psum[4];
    #pragma unroll
    for (int jj = 0; jj < 4; ++jj){
      float m_ = fmaxf(fmaxf(sacc[0][jj], sacc[1][jj]), fmaxf(sacc[2][jj], sacc[3][jj]));
      #pragma unroll
      for (int mk = 1; mk < 16; mk <<= 1) m_ = fmaxf(m_, __shfl_xor(m_, mk, 64));
      float mn = fmaxf(mrun[jj], m_);
      scl[jj] = __expf(mrun[jj] - mn);
      mrun[jj] = mn;
      psum[jj] = 0.f;
    }
    #pragma unroll
    for (int j = 0; j < 4; ++j)
      #pragma unroll
      for (int jj = 0; jj < 4; ++jj){
        float p = __expf(sacc[j][jj] - mrun[jj]);
        sacc[j][jj] = p;
        psum[jj] += p;
      }
    #pragma unroll
    for (int jj = 0; jj < 4; ++jj){
      float ps = psum[jj];
      #pragma unroll
      for (int mk = 1; mk < 16; mk <<= 1) ps += __shfl_xor(ps, mk, 64);
      lrun[jj] = lrun[jj] * scl[jj] + ps;
    }
    #pragma unroll
    for (int n = 0; n < 8; ++n)
      #pragma unroll
      for (int jj = 0; jj < 4; ++jj) acc_o[n][jj] *= scl[jj];
    // P -> LDS (bf16, swizzled)
    unsigned short* Pw = Psm[wave];
    #pragma unroll
    for (int j = 0; j < 4; ++j)
      #pragma unroll
      for (int jj = 0; jj < 4; ++jj){
        int prow = lg * 4 + jj, pcol = j * 16 + lr;
        int bo = prow * 128 + pcol * 2;
        bo ^= (prow & 7) << 4;
        *(unsigned short*)((char*)Pw + bo) = f2bf(sacc[j][jj]);
      }
    __syncthreads();                       // P visible, all waves aligned
    // O += P @ V  (V^T in LDS -> bt-style B frags)
    #pragma unroll
    for (int k2 = 0; k2 < 2; ++k2){
      int bo = lr * 128 + (k2 * 32 + lg * 8) * 2;
      bo ^= (lr & 7) << 4;
      bf16x8 pf = *(const bf16x8*)((const char*)Pw + bo);
      #pragma unroll
      for (int n = 0; n < 8; ++n){
        int dd = n * 16 + lr;
        int vb_ = dd * 128 + (k2 * 32 + lg * 8) * 2;
        vb_ ^= (dd & 7) << 4;
        bf16x8 vf = *(const bf16x8*)((const char*)Vsm + vb_);
        acc_o[n] = __builtin_amdgcn_mfma_f32_16x16x32_bf16(pf, vf, acc_o[n], 0, 0, 0);
      }
    }
  }
  #pragma unroll
  for (int jj = 0; jj < 4; ++jj) lrun[jj] = 1.f / lrun[jj];
  #pragma unroll
  for (int n = 0; n < 8; ++n)
    #pragma unroll
    for (int jj = 0; jj < 4; ++jj){
      int row = q0 + lg * 4 + jj;
      int col = hh * HDIM + n * 16 + lr;
      a2[(size_t)row * NCOL2 + col] = f2bf(acc_o[n][jj] * lrun[jj]);
    }
}

// ------------------------------------------------------------------ launch
extern "C" void kernel_launch(void* const* d_in, const int* in_sizes, int n_in,
                              void* d_out, int out_size, void* d_ws, size_t ws_size,
                              hipStream_t stream){
  const float* x       = (const float*)d_in[0];
  const float* vec     = (const float*)d_in[1];
  const float* pe      = (const float*)d_in[2];
  const float* mod_w   = (const float*)d_in[3];
  const float* mod_b   = (const float*)d_in[4];
  const float* lin1_w  = (const float*)d_in[5];
  const float* lin1_b  = (const float*)d_in[6];
  const float* lin2_w  = (const float*)d_in[7];
  const float* lin2_b  = (const float*)d_in[8];
  const float* q_scale = (const float*)d_in[9];
  const float* k_scale = (const float*)d_in[10];
  float* out = (float*)d_out;

  char* ws = (char*)d_ws;
  size_t off = 0;
  auto alloc = [&](size_t bytes){ void* p = ws + off; off += (bytes + 255) & ~(size_t)255; return p; };
  float* sv            = (float*)alloc((size_t)HID * 4);
  float* mod           = (float*)alloc((size_t)MOD3 * 4);
  unsigned short* xmod = (unsigned short*)alloc((size_t)SEQ * HID * 2);
  unsigned short* wt1  = (unsigned short*)alloc((size_t)NCOL1 * HID * 2);
  unsigned short* wt2  = (unsigned short*)alloc((size_t)HID * NCOL2 * 2);
  float* hbuf          = (float*)alloc((size_t)SEQ * NCOL1 * 4);
  unsigned short* qb   = (unsigned short*)alloc((size_t)NHEADS * SEQ * HDIM * 2);
  unsigned short* kb   = (unsigned short*)alloc((size_t)NHEADS * SEQ * HDIM * 2);
  unsigned short* vb   = (unsigned short*)alloc((size_t)NHEADS * SEQ * HDIM * 2);
  unsigned short* vt   = (unsigned short*)alloc((size_t)NHEADS * SEQ * HDIM * 2);
  unsigned short* a2   = (unsigned short*)alloc((size_t)SEQ * NCOL2 * 2);

  silu_kernel<<<12, 256, 0, stream>>>(vec, sv);
  mod_gemv<<<MOD3 / 32, 256, 0, stream>>>(sv, mod_w, mod_b, mod);
  transpose_f2b<<<dim3(NCOL1 / 64, HID / 64), 256, 0, stream>>>(lin1_w, wt1, HID, NCOL1);
  transpose_f2b<<<dim3(HID / 64, NCOL2 / 64), 256, 0, stream>>>(lin2_w, wt2, NCOL2, HID);
  ln_mod_kernel<<<SEQ, 256, 0, stream>>>(x, mod, xmod);
  gemm_bt<0><<<dim3(NCOL1 / 128, SEQ / 128), 256, 0, stream>>>(
      xmod, wt1, lin1_b, hbuf, nullptr, nullptr, SEQ, NCOL1, HID);
  qkv_prep<<<dim3(SEQ, NHEADS), 64, 0, stream>>>(hbuf, pe, q_scale, k_scale, qb, kb, vb);
  transpose_b2b_head<<<dim3(HDIM / 64, SEQ / 64, NHEADS), 256, 0, stream>>>(vb, vt, SEQ, HDIM);
  gelu_kernel<<<dim3(MLPD / 4 / 256, SEQ), 256, 0, stream>>>(hbuf, a2);
  attn_kernel<<<dim3(SEQ / 64, NHEADS), 256, 0, stream>>>(qb, kb, vt, a2);
  gemm_bt<1><<<dim3(HID / 128, SEQ / 128), 256, 0, stream>>>(
      a2, wt2, lin2_b, out, x, mod + 2 * HID, SEQ, HID, NCOL2);
}